// Round 13
// baseline (181.460 us; speedup 1.0000x reference)
//
#include <hip/hip_runtime.h>
#include <stdint.h>

typedef unsigned short u16;
typedef __attribute__((ext_vector_type(8))) short short8;
typedef __attribute__((ext_vector_type(4))) float floatx4;
typedef __attribute__((ext_vector_type(4))) unsigned short u16x4;
typedef __attribute__((ext_vector_type(2))) unsigned int uint2v;

__device__ __forceinline__ float bf2f(u16 v) {
  union { uint32_t u; float f; } x; x.u = ((uint32_t)v) << 16; return x.f;
}
__device__ __forceinline__ u16 f2bf(float f) {
  union { float f; uint32_t u; } x; x.f = f;
  uint32_t r = x.u + 0x7fffu + ((x.u >> 16) & 1u);
  return (u16)(r >> 16);
}
__device__ __forceinline__ uint32_t fu(float f) {
  union { float f; uint32_t u; } x; x.f = f; return x.u;
}

#define GL2LDS(g, l)                                                          \
  __builtin_amdgcn_global_load_lds(                                           \
      (const __attribute__((address_space(1))) void*)(g),                     \
      (__attribute__((address_space(3))) void*)(l), 16, 0, 0)

#define WAITBAR(N)                                                            \
  asm volatile("s_waitcnt vmcnt(" #N ")\n\ts_barrier" ::: "memory")
#define BARX asm volatile("s_barrier" ::: "memory")
#define VM0BARX asm volatile("s_waitcnt vmcnt(0)\n\ts_barrier" ::: "memory")

// ------- prep: layernorm (blocks 0..4095) + 3 weight transposes (4096..5119) ---
// Transpose rebuilt: 64x64 tiles (1024 blocks, was 4096), transposed-LDS stage,
// and 16B short8 global stores. The old path wrote 8MB of bf16 via PER-LANE
// SCALAR 2B stores (64B/instruction) -- the store-side version of G13.
__global__ __launch_bounds__(256) void prep_k(const float* __restrict__ x,
                                              const float* __restrict__ gamma,
                                              const float* __restrict__ beta,
                                              const float* __restrict__ Wq,
                                              const float* __restrict__ Wkv,
                                              const float* __restrict__ Wo,
                                              u16* __restrict__ xn,
                                              u16* __restrict__ wqkvT,
                                              u16* __restrict__ woT) {
  int bid = blockIdx.x;
  int t = threadIdx.x;
  if (bid < 4096) {
    int row = bid;
    const float* xr = x + (size_t)row * 1024;
    float4 xv = *(const float4*)(xr + t * 4);
    float v0 = xv.x, v1 = xv.y, v2 = xv.z, v3 = xv.w;
    float s = v0 + v1 + v2 + v3;
    float s2 = v0 * v0 + v1 * v1 + v2 * v2 + v3 * v3;
#pragma unroll
    for (int d = 1; d < 64; d <<= 1) {
      s += __shfl_xor(s, d, 64);
      s2 += __shfl_xor(s2, d, 64);
    }
    __shared__ float red[8];
    int lane = t & 63, wv = t >> 6;
    if (lane == 0) { red[wv] = s; red[4 + wv] = s2; }
    __syncthreads();
    s = red[0] + red[1] + red[2] + red[3];
    s2 = red[4] + red[5] + red[6] + red[7];
    float mu = s * (1.0f / 1024.0f);
    float var = s2 * (1.0f / 1024.0f) - mu * mu;
    float rstd = rsqrtf(var + 1e-5f);
    float4 gv = *(const float4*)(gamma + t * 4);
    float4 bv = *(const float4*)(beta + t * 4);
    u16x4 ov;
    ov.x = f2bf((v0 - mu) * rstd * gv.x + bv.x);
    ov.y = f2bf((v1 - mu) * rstd * gv.y + bv.y);
    ov.z = f2bf((v2 - mu) * rstd * gv.z + bv.z);
    ov.w = f2bf((v3 - mu) * rstd * gv.w + bv.w);
    *(u16x4*)(xn + (size_t)row * 1024 + t * 4) = ov;
  } else {
    __shared__ u16 ldst[64][72];  // 9 KB; 72-u16 rows keep short8 reads aligned
    int wb = bid - 4096;          // 64x64 tile index, 0..1023
    const float* in;
    u16* outp;
    int C;
    if (wb < 256) { in = Wq; outp = wqkvT; C = 1024; }
    else if (wb < 768) { wb -= 256; in = Wkv; outp = wqkvT + 1024 * 1024; C = 2048; }
    else { wb -= 768; in = Wo; outp = woT; C = 1024; }
    int nbx = C >> 6;
    int c0 = (wb % nbx) * 64, r0 = (wb / nbx) * 64;
    int rt = t >> 2;          // input row within tile, 0..63
    int ci = (t & 3) * 16;    // input col offset, {0,16,32,48}
    const float* ip = in + (size_t)(r0 + rt) * C + c0 + ci;
#pragma unroll
    for (int q = 0; q < 4; q++) {
      float4 v = *(const float4*)(ip + q * 4);
      ldst[ci + q * 4 + 0][rt] = f2bf(v.x);
      ldst[ci + q * 4 + 1][rt] = f2bf(v.y);
      ldst[ci + q * 4 + 2][rt] = f2bf(v.z);
      ldst[ci + q * 4 + 3][rt] = f2bf(v.w);
    }
    __syncthreads();
    int ct = t >> 2;          // output row within tile (= input col), 0..63
    int ri = (t & 3) * 16;    // output col offset (= input row), {0,16,32,48}
    u16* op = outp + (size_t)(c0 + ct) * 1024 + r0 + ri;
    *(short8*)(op) = *(const short8*)&ldst[ct][ri];
    *(short8*)(op + 8) = *(const short8*)&ldst[ct][ri + 8];
  }
}

// ------- GEMM1, 128x384 tile, 8 waves, BK=64, EXACT 256-block fill ------------
// (kept from r8 -- isolated delta vs r7 was ~-7us: grid 8x32 = 256 equal blocks
// fills all 256 CUs; the 256x256 grid left 64 CUs idle.)
__global__ __launch_bounds__(512, 1) void gemm_qkv_k(const u16* __restrict__ A,
                                                     const u16* __restrict__ BT,
                                                     u16* __restrict__ C) {
  __shared__ __align__(16) u16 sA[2][128 * 64];  // 16 KB per buf
  __shared__ __align__(16) u16 sB[2][384 * 64];  // 48 KB per buf
  int tid = threadIdx.x;
  int w = tid >> 6, l = tid & 63;
  int lr = l & 15, lq = l >> 4;
  int wm = w >> 1, wn = w & 1;
  int bm = blockIdx.y * 128;
  int bn = blockIdx.x * 384;
  floatx4 acc[2][12] = {};
  int gcol = ((tid & 7) ^ ((tid >> 3) & 7)) * 8;
  int strow = tid >> 3;
  int t8 = tid * 8;
  const u16* gA = A + (size_t)(bm + strow) * 1024 + gcol;
  const u16* gB = BT + (size_t)(bn + strow) * 1024 + gcol;
  int csw = (lr & 7) << 3;
  int ar = (wm * 32 + lr) * 64;
  int br = (wn * 192 + lr) * 64;

#define ST_A(bi)                                                              \
  { GL2LDS(gA, &sA[bi][t8]); GL2LDS(gA + 65536, &sA[bi][t8 + 4096]); }
#define ST_B(bi)                                                              \
  { GL2LDS(gB, &sB[bi][t8]);                                                  \
    GL2LDS(gB + 65536, &sB[bi][t8 + 4096]);                                   \
    GL2LDS(gB + 131072, &sB[bi][t8 + 8192]);                                  \
    GL2LDS(gB + 196608, &sB[bi][t8 + 12288]);                                 \
    GL2LDS(gB + 262144, &sB[bi][t8 + 16384]);                                 \
    GL2LDS(gB + 327680, &sB[bi][t8 + 20480]); }
#define HALF(p, kh)                                                           \
  {                                                                           \
    int co_ = ((kh)*32 + lq * 8) ^ csw;                                       \
    short8 a0_ = *(const short8*)&sA[p][ar + co_];                            \
    short8 a1_ = *(const short8*)&sA[p][ar + 1024 + co_];                     \
    _Pragma("unroll") for (int g = 0; g < 3; g++) {                           \
      short8 b0_ = *(const short8*)&sB[p][br + (g * 4 + 0) * 1024 + co_];     \
      short8 b1_ = *(const short8*)&sB[p][br + (g * 4 + 1) * 1024 + co_];     \
      short8 b2_ = *(const short8*)&sB[p][br + (g * 4 + 2) * 1024 + co_];     \
      short8 b3_ = *(const short8*)&sB[p][br + (g * 4 + 3) * 1024 + co_];     \
      acc[0][g*4+0] = __builtin_amdgcn_mfma_f32_16x16x32_bf16(a0_, b0_, acc[0][g*4+0], 0, 0, 0); \
      acc[1][g*4+0] = __builtin_amdgcn_mfma_f32_16x16x32_bf16(a1_, b0_, acc[1][g*4+0], 0, 0, 0); \
      acc[0][g*4+1] = __builtin_amdgcn_mfma_f32_16x16x32_bf16(a0_, b1_, acc[0][g*4+1], 0, 0, 0); \
      acc[1][g*4+1] = __builtin_amdgcn_mfma_f32_16x16x32_bf16(a1_, b1_, acc[1][g*4+1], 0, 0, 0); \
      acc[0][g*4+2] = __builtin_amdgcn_mfma_f32_16x16x32_bf16(a0_, b2_, acc[0][g*4+2], 0, 0, 0); \
      acc[1][g*4+2] = __builtin_amdgcn_mfma_f32_16x16x32_bf16(a1_, b2_, acc[1][g*4+2], 0, 0, 0); \
      acc[0][g*4+3] = __builtin_amdgcn_mfma_f32_16x16x32_bf16(a0_, b3_, acc[0][g*4+3], 0, 0, 0); \
      acc[1][g*4+3] = __builtin_amdgcn_mfma_f32_16x16x32_bf16(a1_, b3_, acc[1][g*4+3], 0, 0, 0); \
    }                                                                         \
  }
#define KT(p, q, DOST)                                                        \
  {                                                                           \
    if (DOST) { ST_A(q); ST_B(q); gA += 64; gB += 64; }                       \
    BARX; __builtin_amdgcn_s_setprio(1);                                      \
    HALF(p, 0);                                                               \
    __builtin_amdgcn_s_setprio(0); BARX;                                      \
    __builtin_amdgcn_s_setprio(1);                                            \
    HALF(p, 1);                                                               \
    __builtin_amdgcn_s_setprio(0); VM0BARX;                                   \
  }

  ST_A(0); ST_B(0); gA += 64; gB += 64;  // K-tile 0
  VM0BARX;
#pragma unroll 1
  for (int t = 0; t < 7; ++t) {  // K-tiles 0..13
    KT(0, 1, 1);
    KT(1, 0, 1);
  }
  KT(0, 1, 1);  // tile 14, stages 15
  KT(1, 0, 0);  // tile 15

  // epilogue: per 64-col head group (sec uniform per head)
#pragma unroll
  for (int nig = 0; nig < 3; nig++) {
    int col0 = bn + wn * 192 + nig * 64;
    int sec = col0 >> 10;  // 0=q, 1=k, 2=v
    if (sec == 2) {
#pragma unroll
      for (int p4 = 0; p4 < 4; p4++) {
        int ni = nig * 4 + p4;
        int col = col0 + p4 * 16 + lr;
        int cv = col - 2048;  // h*64 + d
#pragma unroll
        for (int mi = 0; mi < 2; mi++) {
          int row = bm + wm * 32 + mi * 16 + lq * 4;  // 4-aligned token row
          int bq = row >> 11;
          int n = row & 2047;
          int bh = (bq << 4) | (cv >> 6);
          int d = cv & 63;
          size_t L = ((size_t)(bh * 64 + d) << 11) + n;
          u16x4 ov;
          ov.x = f2bf(acc[mi][ni][0]);
          ov.y = f2bf(acc[mi][ni][1]);
          ov.z = f2bf(acc[mi][ni][2]);
          ov.w = f2bf(acc[mi][ni][3]);
          *(u16x4*)(C + (L >> 10) * 3072 + 2048 + (L & 1023)) = ov;
        }
      }
    } else {
      float QS = (sec == 0) ? 0.125f * 1.44269504088896f : 1.0f;
#pragma unroll
      for (int np = 0; np < 2; np++) {
        int i = np * 16 + lr;  // head-local rotary index, [0,32)
        float invf = exp2f(-(float)i * 0.4152410118609203f);  // 10000^(-i/32)
#pragma unroll
        for (int mi = 0; mi < 2; mi++)
#pragma unroll
          for (int r = 0; r < 4; r++) {
            int row = bm + wm * 32 + mi * 16 + lq * 4 + r;
            int n = row & 2047;
            float ang = (float)n * invf;
            float s_, c_;
            __sincosf(ang, &s_, &c_);
            float x1 = acc[mi][nig * 4 + np][r];
            float x2 = acc[mi][nig * 4 + np + 2][r];
            int col = col0 + np * 16 + lr;
            C[(size_t)row * 3072 + col] = f2bf((x1 * c_ - x2 * s_) * QS);
            C[(size_t)row * 3072 + col + 32] = f2bf((x2 * c_ + x1 * s_) * QS);
          }
      }
    }
  }
}

// ------- GEMM2 (out-proj, fp32 out): 128x128 tile, 8 waves, BK=64 -------------
// (r12 rebuild on the gemm_qkv schedule: 256 equal blocks, conflict-free
// swizzled 64-wide LDS rows, one vmcnt(0) boundary per K-tile.)
__global__ __launch_bounds__(512, 1) void gemm64_bf16_k(const u16* __restrict__ A,
                                                        const u16* __restrict__ BT,
                                                        float* __restrict__ C) {
  __shared__ __align__(16) u16 sA[2][128 * 64];  // 16 KB per buf
  __shared__ __align__(16) u16 sB[2][128 * 64];  // 16 KB per buf
  int tid = threadIdx.x;
  int w = tid >> 6, l = tid & 63;
  int lr = l & 15, lq = l >> 4;
  int wm = w >> 1, wn = w & 1;
  int bm = blockIdx.y * 128;
  int bn = blockIdx.x * 128;
  floatx4 acc[2][4] = {};
  int gcol = ((tid & 7) ^ ((tid >> 3) & 7)) * 8;
  int strow = tid >> 3;
  int t8 = tid * 8;
  const u16* gA = A + (size_t)(bm + strow) * 1024 + gcol;
  const u16* gB = BT + (size_t)(bn + strow) * 1024 + gcol;
  int csw = (lr & 7) << 3;
  int ar = (wm * 32 + lr) * 64;
  int br = (wn * 64 + lr) * 64;

#define ST_A2(bi)                                                             \
  { GL2LDS(gA, &sA[bi][t8]); GL2LDS(gA + 65536, &sA[bi][t8 + 4096]); }
#define ST_B2(bi)                                                             \
  { GL2LDS(gB, &sB[bi][t8]); GL2LDS(gB + 65536, &sB[bi][t8 + 4096]); }
#define HALF2(p, kh)                                                          \
  {                                                                           \
    int co_ = ((kh)*32 + lq * 8) ^ csw;                                       \
    short8 a0_ = *(const short8*)&sA[p][ar + co_];                            \
    short8 a1_ = *(const short8*)&sA[p][ar + 1024 + co_];                     \
    short8 b0_ = *(const short8*)&sB[p][br + 0 + co_];                        \
    short8 b1_ = *(const short8*)&sB[p][br + 1024 + co_];                     \
    short8 b2_ = *(const short8*)&sB[p][br + 2048 + co_];                     \
    short8 b3_ = *(const short8*)&sB[p][br + 3072 + co_];                     \
    acc[0][0] = __builtin_amdgcn_mfma_f32_16x16x32_bf16(a0_, b0_, acc[0][0], 0, 0, 0); \
    acc[1][0] = __builtin_amdgcn_mfma_f32_16x16x32_bf16(a1_, b0_, acc[1][0], 0, 0, 0); \
    acc[0][1] = __builtin_amdgcn_mfma_f32_16x16x32_bf16(a0_, b1_, acc[0][1], 0, 0, 0); \
    acc[1][1] = __builtin_amdgcn_mfma_f32_16x16x32_bf16(a1_, b1_, acc[1][1], 0, 0, 0); \
    acc[0][2] = __builtin_amdgcn_mfma_f32_16x16x32_bf16(a0_, b2_, acc[0][2], 0, 0, 0); \
    acc[1][2] = __builtin_amdgcn_mfma_f32_16x16x32_bf16(a1_, b2_, acc[1][2], 0, 0, 0); \
    acc[0][3] = __builtin_amdgcn_mfma_f32_16x16x32_bf16(a0_, b3_, acc[0][3], 0, 0, 0); \
    acc[1][3] = __builtin_amdgcn_mfma_f32_16x16x32_bf16(a1_, b3_, acc[1][3], 0, 0, 0); \
  }
#define KT2(p, q, DOST)                                                       \
  {                                                                           \
    if (DOST) { ST_A2(q); ST_B2(q); gA += 64; gB += 64; }                     \
    BARX; __builtin_amdgcn_s_setprio(1);                                      \
    HALF2(p, 0);                                                              \
    __builtin_amdgcn_s_setprio(0); BARX;                                      \
    __builtin_amdgcn_s_setprio(1);                                            \
    HALF2(p, 1);                                                              \
    __builtin_amdgcn_s_setprio(0); VM0BARX;                                   \
  }

  ST_A2(0); ST_B2(0); gA += 64; gB += 64;  // K-tile 0
  VM0BARX;
#pragma unroll 1
  for (int t = 0; t < 7; ++t) {  // K-tiles 0..13
    KT2(0, 1, 1);
    KT2(1, 0, 1);
  }
  KT2(0, 1, 1);  // tile 14, stages 15
  KT2(1, 0, 0);  // tile 15

#pragma unroll
  for (int mi = 0; mi < 2; mi++)
#pragma unroll
    for (int ni = 0; ni < 4; ni++) {
      int row = bm + wm * 32 + mi * 16 + lq * 4;
      int col = bn + wn * 64 + ni * 16 + lr;
#pragma unroll
      for (int r = 0; r < 4; r++)
        C[(size_t)(row + r) * 1024 + col] = acc[mi][ni][r];
    }
}

// ------- flash attention (causal), linear softmax, exp2 domain -----------------
// r11-measured 47.3us version, kept verbatim: 4 blocks/CU, balanced remap,
// running staging pointers, no softmax shift.
#define LPT 64
__device__ __forceinline__ void attn_tile2(const u16* lK, const u16* lV, u16* lp,
                                           const short8* aq, floatx4* o,
                                           float& l_i, int lr, int lq,
                                           bool diag, int q0, int k0g,
                                           short8 ones) {
  floatx4 s[4];
#pragma unroll
  for (int ni = 0; ni < 4; ni++) {
    floatx4 a = {};
#pragma unroll
    for (int kc = 0; kc < 2; kc++) {
      int R = ni * 16 + lr;
      int c8 = (kc * 4 + lq) ^ (R & 7);
      short8 kf = *(const short8*)&lK[R * 64 + c8 * 8];
      a = __builtin_amdgcn_mfma_f32_16x16x32_bf16(kf, aq[kc], a, 0, 0, 0);
    }
    s[ni] = a;
  }
  if (diag) {
    int qg = q0 + lr;
#pragma unroll
    for (int ni = 0; ni < 4; ni++)
#pragma unroll
      for (int r = 0; r < 4; r++) {
        int kg = k0g + ni * 16 + lq * 4 + r;
        if (kg > qg) s[ni][r] = -1e30f;
      }
  }
  int swz = (lr & 7) << 3;
#pragma unroll
  for (int ni = 0; ni < 4; ni++) {
    float p0 = exp2f(s[ni][0]), p1 = exp2f(s[ni][1]);
    float p2 = exp2f(s[ni][2]), p3 = exp2f(s[ni][3]);
    uint2v dw;
    dw.x = __builtin_amdgcn_perm(fu(p1), fu(p0), 0x07060302u);
    dw.y = __builtin_amdgcn_perm(fu(p3), fu(p2), 0x07060302u);
    *(uint2v*)&lp[lr * LPT + ((ni * 16 + lq * 4) ^ swz)] = dw;
  }
  short8 pb0 = *(const short8*)&lp[lr * LPT + ((lq * 8) ^ swz)];
  short8 pb1 = *(const short8*)&lp[lr * LPT + ((32 + lq * 8) ^ swz)];
  floatx4 z = {};
  z = __builtin_amdgcn_mfma_f32_16x16x32_bf16(ones, pb0, z, 0, 0, 0);
  z = __builtin_amdgcn_mfma_f32_16x16x32_bf16(ones, pb1, z, 0, 0, 0);
  l_i += z[0];
#pragma unroll
  for (int di = 0; di < 4; di++) {
    int R = di * 16 + lr;
    int c80 = lq ^ (R & 7);
    int c81 = (4 + lq) ^ (R & 7);
    short8 v0 = *(const short8*)&lV[R * 64 + c80 * 8];
    o[di] = __builtin_amdgcn_mfma_f32_16x16x32_bf16(v0, pb0, o[di], 0, 0, 0);
    short8 v1 = *(const short8*)&lV[R * 64 + c81 * 8];
    o[di] = __builtin_amdgcn_mfma_f32_16x16x32_bf16(v1, pb1, o[di], 0, 0, 0);
  }
}

__global__ __launch_bounds__(256) void attn_k(const u16* __restrict__ qkv,
                                              u16* __restrict__ out) {
  __shared__ __align__(16) u16 lK[2][64 * 64];
  __shared__ __align__(16) u16 lV[2][64 * 64];
  __shared__ __align__(16) u16 lP[4][16 * LPT];
  int bh = blockIdx.x;
  int b = bh >> 4, h = bh & 15;
  int y = blockIdx.y;
  int g = y >> 3, o_ = y & 7;
  int j = (g & 1) ? ((g << 3) + 7 - o_) : y;  // balanced causal remap
  int tid = threadIdx.x;
  int w = tid >> 6, l = tid & 63;
  int lr = l & 15, lq = l >> 4;
  int q0 = j * 64 + w * 16;
  const u16* qb = qkv + (size_t)b * 2048 * 3072 + h * 64;
  const u16* kb = qkv + (size_t)b * 2048 * 3072 + 1024 + h * 64;
  int bh64 = bh * 64;
  short8 aq[2];
  aq[0] = *(const short8*)(qb + (size_t)(q0 + lr) * 3072 + lq * 8);
  aq[1] = *(const short8*)(qb + (size_t)(q0 + lr) * 3072 + 32 + lq * 8);
  short8 ones;
#pragma unroll
  for (int i = 0; i < 8; i++) ones[i] = (short)0x3F80;
  floatx4 o[4] = {};
  float l_ = 0.0f;
  int srow8 = l >> 3;
  int sc8 = (l & 7) ^ srow8;
  u16* lp = &lP[w][0];
  // running staging pointers (tile to stage next)
  int row0 = w * 8 + srow8;        // m = w
  int row1 = (w + 4) * 8 + srow8;  // m = w+4
  const u16* kp0 = kb + (size_t)row0 * 3072 + sc8 * 8;
  const u16* kp1 = kb + (size_t)row1 * 3072 + sc8 * 8;
  const u16* vp0 = qkv + (size_t)((bh64 + row0) * 2) * 3072 + 2048 + sc8 * 8;
  const u16* vp1 = qkv + (size_t)((bh64 + row1) * 2) * 3072 + 2048 + sc8 * 8;
  auto stage = [&](int bufi) {
    GL2LDS(kp0, &lK[bufi][w * 512]);
    GL2LDS(vp0, &lV[bufi][w * 512]);
    GL2LDS(kp1, &lK[bufi][(w + 4) * 512]);
    GL2LDS(vp1, &lV[bufi][(w + 4) * 512]);
  };
  auto advance = [&](int ktStaged) {
    kp0 += 196608; kp1 += 196608;
    int dv = (((ktStaged + 1) & 15) == 0) ? 2112 : 64;
    vp0 += dv; vp1 += dv;
  };
  stage(0);
  advance(0);
  for (int kt = 0; kt <= j; ++kt) {
    int cur = kt & 1;
    __syncthreads();  // publishes buf[cur], guards reuse of buf[cur^1]
    if (kt < j) { stage(cur ^ 1); advance(kt + 1); }
    attn_tile2(lK[cur], lV[cur], lp, aq, o, l_, lr, lq, kt == j, q0, kt * 64,
               ones);
  }
  float rl = 1.0f / l_;
#pragma unroll
  for (int di = 0; di < 4; di++) {
    uint2v dw;
    u16 a0 = f2bf(o[di][0] * rl), a1 = f2bf(o[di][1] * rl);
    u16 a2 = f2bf(o[di][2] * rl), a3 = f2bf(o[di][3] * rl);
    dw.x = (uint32_t)a0 | ((uint32_t)a1 << 16);
    dw.y = (uint32_t)a2 | ((uint32_t)a3 << 16);
    int dcol = h * 64 + di * 16 + lq * 4;
    *(uint2v*)(out + ((size_t)(b * 2048 + q0 + lr)) * 1024 + dcol) = dw;
  }
}

// ------- launch ---------------------------------------------------------------
extern "C" void kernel_launch(void* const* d_in, const int* in_sizes, int n_in,
                              void* d_out, int out_size, void* d_ws, size_t ws_size,
                              hipStream_t stream) {
  const float* x = (const float*)d_in[0];
  const float* gamma = (const float*)d_in[1];
  const float* beta = (const float*)d_in[2];
  const float* Wq = (const float*)d_in[3];
  const float* Wkv = (const float*)d_in[4];
  const float* Wo = (const float*)d_in[5];
  float* out = (float*)d_out;
  char* ws = (char*)d_ws;

  u16* qkv = (u16*)(ws);               // 4096x3072 bf16 = 24 MiB (v-slice holds packed vT)
  u16* wqkvT = (u16*)(ws + 25165824);  // 3072x1024 = 6 MiB
  u16* woT = (u16*)(ws + 31457280);    // 1024x1024 = 2 MiB
  u16* xn = (u16*)(ws + 33554432);     // 4096x1024 = 8 MiB
  u16* attn_out = xn;                  // alias: xn dead after gemm_qkv (4096x1024 bf16)

  prep_k<<<5120, 256, 0, stream>>>(x, gamma, beta, Wq, Wkv, Wo, xn, wqkvT, woT);
  gemm_qkv_k<<<dim3(8, 32), 512, 0, stream>>>(xn, wqkvT, qkv);
  attn_k<<<dim3(32, 32), 256, 0, stream>>>(qkv, attn_out);
  gemm64_bf16_k<<<dim3(8, 32), 512, 0, stream>>>(attn_out, woT, out);
}

// Round 14
// 178.877 us; speedup vs baseline: 1.0144x; 1.0144x over previous
//
#include <hip/hip_runtime.h>
#include <stdint.h>

typedef unsigned short u16;
typedef __attribute__((ext_vector_type(8))) short short8;
typedef __attribute__((ext_vector_type(4))) float floatx4;
typedef __attribute__((ext_vector_type(4))) unsigned short u16x4;
typedef __attribute__((ext_vector_type(2))) unsigned int uint2v;

__device__ __forceinline__ float bf2f(u16 v) {
  union { uint32_t u; float f; } x; x.u = ((uint32_t)v) << 16; return x.f;
}
__device__ __forceinline__ u16 f2bf(float f) {
  union { float f; uint32_t u; } x; x.f = f;
  uint32_t r = x.u + 0x7fffu + ((x.u >> 16) & 1u);
  return (u16)(r >> 16);
}
__device__ __forceinline__ uint32_t fu(float f) {
  union { float f; uint32_t u; } x; x.f = f; return x.u;
}

#define GL2LDS(g, l)                                                          \
  __builtin_amdgcn_global_load_lds(                                           \
      (const __attribute__((address_space(1))) void*)(g),                     \
      (__attribute__((address_space(3))) void*)(l), 16, 0, 0)

#define WAITBAR(N)                                                            \
  asm volatile("s_waitcnt vmcnt(" #N ")\n\ts_barrier" ::: "memory")
#define BARX asm volatile("s_barrier" ::: "memory")
#define VM0BARX asm volatile("s_waitcnt vmcnt(0)\n\ts_barrier" ::: "memory")

// XCD-locality remap (T1): 256-block 1D grid onto a 32(bm) x 8(bn) tile grid.
// XCD = bid%8 (round-robin); give each XCD an 8bm x 4bn RECTANGLE instead of a
// full bn-column: per-XCD working set 8.75 MB -> 5 MB (qkv) / 3 MB (gemm64).
// Bijection: bmi = (x[2:1], s[2:0]), bni = (x[0], s[4:3]).
__device__ __forceinline__ void xcd_remap(int bid, int& bmi, int& bni) {
  int x = bid & 7, s = bid >> 3;
  bmi = ((x >> 1) << 3) | (s & 7);
  bni = ((x & 1) << 2) | (s >> 3);
}

// ------- prep: layernorm (blocks 0..4095) + 3 weight transposes (4096..5119) ---
__global__ __launch_bounds__(256) void prep_k(const float* __restrict__ x,
                                              const float* __restrict__ gamma,
                                              const float* __restrict__ beta,
                                              const float* __restrict__ Wq,
                                              const float* __restrict__ Wkv,
                                              const float* __restrict__ Wo,
                                              u16* __restrict__ xn,
                                              u16* __restrict__ wqkvT,
                                              u16* __restrict__ woT) {
  int bid = blockIdx.x;
  int t = threadIdx.x;
  if (bid < 4096) {
    int row = bid;
    const float* xr = x + (size_t)row * 1024;
    float4 xv = *(const float4*)(xr + t * 4);
    float v0 = xv.x, v1 = xv.y, v2 = xv.z, v3 = xv.w;
    float s = v0 + v1 + v2 + v3;
    float s2 = v0 * v0 + v1 * v1 + v2 * v2 + v3 * v3;
#pragma unroll
    for (int d = 1; d < 64; d <<= 1) {
      s += __shfl_xor(s, d, 64);
      s2 += __shfl_xor(s2, d, 64);
    }
    __shared__ float red[8];
    int lane = t & 63, wv = t >> 6;
    if (lane == 0) { red[wv] = s; red[4 + wv] = s2; }
    __syncthreads();
    s = red[0] + red[1] + red[2] + red[3];
    s2 = red[4] + red[5] + red[6] + red[7];
    float mu = s * (1.0f / 1024.0f);
    float var = s2 * (1.0f / 1024.0f) - mu * mu;
    float rstd = rsqrtf(var + 1e-5f);
    float4 gv = *(const float4*)(gamma + t * 4);
    float4 bv = *(const float4*)(beta + t * 4);
    u16x4 ov;
    ov.x = f2bf((v0 - mu) * rstd * gv.x + bv.x);
    ov.y = f2bf((v1 - mu) * rstd * gv.y + bv.y);
    ov.z = f2bf((v2 - mu) * rstd * gv.z + bv.z);
    ov.w = f2bf((v3 - mu) * rstd * gv.w + bv.w);
    *(u16x4*)(xn + (size_t)row * 1024 + t * 4) = ov;
  } else {
    __shared__ u16 ldst[64][72];  // 9 KB; 72-u16 rows keep short8 reads aligned
    int wb = bid - 4096;          // 64x64 tile index, 0..1023
    const float* in;
    u16* outp;
    int C;
    if (wb < 256) { in = Wq; outp = wqkvT; C = 1024; }
    else if (wb < 768) { wb -= 256; in = Wkv; outp = wqkvT + 1024 * 1024; C = 2048; }
    else { wb -= 768; in = Wo; outp = woT; C = 1024; }
    int nbx = C >> 6;
    int c0 = (wb % nbx) * 64, r0 = (wb / nbx) * 64;
    int rt = t >> 2;          // input row within tile, 0..63
    int ci = (t & 3) * 16;    // input col offset, {0,16,32,48}
    const float* ip = in + (size_t)(r0 + rt) * C + c0 + ci;
#pragma unroll
    for (int q = 0; q < 4; q++) {
      float4 v = *(const float4*)(ip + q * 4);
      ldst[ci + q * 4 + 0][rt] = f2bf(v.x);
      ldst[ci + q * 4 + 1][rt] = f2bf(v.y);
      ldst[ci + q * 4 + 2][rt] = f2bf(v.z);
      ldst[ci + q * 4 + 3][rt] = f2bf(v.w);
    }
    __syncthreads();
    int ct = t >> 2;          // output row within tile (= input col), 0..63
    int ri = (t & 3) * 16;    // output col offset (= input row), {0,16,32,48}
    u16* op = outp + (size_t)(c0 + ct) * 1024 + r0 + ri;
    *(short8*)(op) = *(const short8*)&ldst[ct][ri];
    *(short8*)(op + 8) = *(const short8*)&ldst[ct][ri + 8];
  }
}

// ------- GEMM1, 128x384 tile, 8 waves, BK=64, 256-block fill + XCD remap ------
__global__ __launch_bounds__(512, 1) void gemm_qkv_k(const u16* __restrict__ A,
                                                     const u16* __restrict__ BT,
                                                     u16* __restrict__ C) {
  __shared__ __align__(16) u16 sA[2][128 * 64];  // 16 KB per buf
  __shared__ __align__(16) u16 sB[2][384 * 64];  // 48 KB per buf
  int tid = threadIdx.x;
  int w = tid >> 6, l = tid & 63;
  int lr = l & 15, lq = l >> 4;
  int wm = w >> 1, wn = w & 1;
  int bmi, bni;
  xcd_remap(blockIdx.x, bmi, bni);
  int bm = bmi * 128;
  int bn = bni * 384;
  floatx4 acc[2][12] = {};
  int gcol = ((tid & 7) ^ ((tid >> 3) & 7)) * 8;
  int strow = tid >> 3;
  int t8 = tid * 8;
  const u16* gA = A + (size_t)(bm + strow) * 1024 + gcol;
  const u16* gB = BT + (size_t)(bn + strow) * 1024 + gcol;
  int csw = (lr & 7) << 3;
  int ar = (wm * 32 + lr) * 64;
  int br = (wn * 192 + lr) * 64;

#define ST_A(bi)                                                              \
  { GL2LDS(gA, &sA[bi][t8]); GL2LDS(gA + 65536, &sA[bi][t8 + 4096]); }
#define ST_B(bi)                                                              \
  { GL2LDS(gB, &sB[bi][t8]);                                                  \
    GL2LDS(gB + 65536, &sB[bi][t8 + 4096]);                                   \
    GL2LDS(gB + 131072, &sB[bi][t8 + 8192]);                                  \
    GL2LDS(gB + 196608, &sB[bi][t8 + 12288]);                                 \
    GL2LDS(gB + 262144, &sB[bi][t8 + 16384]);                                 \
    GL2LDS(gB + 327680, &sB[bi][t8 + 20480]); }
#define HALF(p, kh)                                                           \
  {                                                                           \
    int co_ = ((kh)*32 + lq * 8) ^ csw;                                       \
    short8 a0_ = *(const short8*)&sA[p][ar + co_];                            \
    short8 a1_ = *(const short8*)&sA[p][ar + 1024 + co_];                     \
    _Pragma("unroll") for (int g = 0; g < 3; g++) {                           \
      short8 b0_ = *(const short8*)&sB[p][br + (g * 4 + 0) * 1024 + co_];     \
      short8 b1_ = *(const short8*)&sB[p][br + (g * 4 + 1) * 1024 + co_];     \
      short8 b2_ = *(const short8*)&sB[p][br + (g * 4 + 2) * 1024 + co_];     \
      short8 b3_ = *(const short8*)&sB[p][br + (g * 4 + 3) * 1024 + co_];     \
      acc[0][g*4+0] = __builtin_amdgcn_mfma_f32_16x16x32_bf16(a0_, b0_, acc[0][g*4+0], 0, 0, 0); \
      acc[1][g*4+0] = __builtin_amdgcn_mfma_f32_16x16x32_bf16(a1_, b0_, acc[1][g*4+0], 0, 0, 0); \
      acc[0][g*4+1] = __builtin_amdgcn_mfma_f32_16x16x32_bf16(a0_, b1_, acc[0][g*4+1], 0, 0, 0); \
      acc[1][g*4+1] = __builtin_amdgcn_mfma_f32_16x16x32_bf16(a1_, b1_, acc[1][g*4+1], 0, 0, 0); \
      acc[0][g*4+2] = __builtin_amdgcn_mfma_f32_16x16x32_bf16(a0_, b2_, acc[0][g*4+2], 0, 0, 0); \
      acc[1][g*4+2] = __builtin_amdgcn_mfma_f32_16x16x32_bf16(a1_, b2_, acc[1][g*4+2], 0, 0, 0); \
      acc[0][g*4+3] = __builtin_amdgcn_mfma_f32_16x16x32_bf16(a0_, b3_, acc[0][g*4+3], 0, 0, 0); \
      acc[1][g*4+3] = __builtin_amdgcn_mfma_f32_16x16x32_bf16(a1_, b3_, acc[1][g*4+3], 0, 0, 0); \
    }                                                                         \
  }
#define KT(p, q, DOST)                                                        \
  {                                                                           \
    if (DOST) { ST_A(q); ST_B(q); gA += 64; gB += 64; }                       \
    BARX; __builtin_amdgcn_s_setprio(1);                                      \
    HALF(p, 0);                                                               \
    __builtin_amdgcn_s_setprio(0); BARX;                                      \
    __builtin_amdgcn_s_setprio(1);                                            \
    HALF(p, 1);                                                               \
    __builtin_amdgcn_s_setprio(0); VM0BARX;                                   \
  }

  ST_A(0); ST_B(0); gA += 64; gB += 64;  // K-tile 0
  VM0BARX;
#pragma unroll 1
  for (int t = 0; t < 7; ++t) {  // K-tiles 0..13
    KT(0, 1, 1);
    KT(1, 0, 1);
  }
  KT(0, 1, 1);  // tile 14, stages 15
  KT(1, 0, 0);  // tile 15

  // epilogue: per 64-col head group (sec uniform per head)
#pragma unroll
  for (int nig = 0; nig < 3; nig++) {
    int col0 = bn + wn * 192 + nig * 64;
    int sec = col0 >> 10;  // 0=q, 1=k, 2=v
    if (sec == 2) {
#pragma unroll
      for (int p4 = 0; p4 < 4; p4++) {
        int ni = nig * 4 + p4;
        int col = col0 + p4 * 16 + lr;
        int cv = col - 2048;  // h*64 + d
#pragma unroll
        for (int mi = 0; mi < 2; mi++) {
          int row = bm + wm * 32 + mi * 16 + lq * 4;  // 4-aligned token row
          int bq = row >> 11;
          int n = row & 2047;
          int bh = (bq << 4) | (cv >> 6);
          int d = cv & 63;
          size_t L = ((size_t)(bh * 64 + d) << 11) + n;
          u16x4 ov;
          ov.x = f2bf(acc[mi][ni][0]);
          ov.y = f2bf(acc[mi][ni][1]);
          ov.z = f2bf(acc[mi][ni][2]);
          ov.w = f2bf(acc[mi][ni][3]);
          *(u16x4*)(C + (L >> 10) * 3072 + 2048 + (L & 1023)) = ov;
        }
      }
    } else {
      float QS = (sec == 0) ? 0.125f * 1.44269504088896f : 1.0f;
#pragma unroll
      for (int np = 0; np < 2; np++) {
        int i = np * 16 + lr;  // head-local rotary index, [0,32)
        float invf = exp2f(-(float)i * 0.4152410118609203f);  // 10000^(-i/32)
#pragma unroll
        for (int mi = 0; mi < 2; mi++)
#pragma unroll
          for (int r = 0; r < 4; r++) {
            int row = bm + wm * 32 + mi * 16 + lq * 4 + r;
            int n = row & 2047;
            float ang = (float)n * invf;
            float s_, c_;
            __sincosf(ang, &s_, &c_);
            float x1 = acc[mi][nig * 4 + np][r];
            float x2 = acc[mi][nig * 4 + np + 2][r];
            int col = col0 + np * 16 + lr;
            C[(size_t)row * 3072 + col] = f2bf((x1 * c_ - x2 * s_) * QS);
            C[(size_t)row * 3072 + col + 32] = f2bf((x2 * c_ + x1 * s_) * QS);
          }
      }
    }
  }
}

// ------- GEMM2 (out-proj, fp32 out): 128x128 tile, 8 waves, BK=64 + XCD remap -
__global__ __launch_bounds__(512, 1) void gemm64_bf16_k(const u16* __restrict__ A,
                                                        const u16* __restrict__ BT,
                                                        float* __restrict__ C) {
  __shared__ __align__(16) u16 sA[2][128 * 64];  // 16 KB per buf
  __shared__ __align__(16) u16 sB[2][128 * 64];  // 16 KB per buf
  int tid = threadIdx.x;
  int w = tid >> 6, l = tid & 63;
  int lr = l & 15, lq = l >> 4;
  int wm = w >> 1, wn = w & 1;
  int bmi, bni;
  xcd_remap(blockIdx.x, bmi, bni);
  int bm = bmi * 128;
  int bn = bni * 128;
  floatx4 acc[2][4] = {};
  int gcol = ((tid & 7) ^ ((tid >> 3) & 7)) * 8;
  int strow = tid >> 3;
  int t8 = tid * 8;
  const u16* gA = A + (size_t)(bm + strow) * 1024 + gcol;
  const u16* gB = BT + (size_t)(bn + strow) * 1024 + gcol;
  int csw = (lr & 7) << 3;
  int ar = (wm * 32 + lr) * 64;
  int br = (wn * 64 + lr) * 64;

#define ST_A2(bi)                                                             \
  { GL2LDS(gA, &sA[bi][t8]); GL2LDS(gA + 65536, &sA[bi][t8 + 4096]); }
#define ST_B2(bi)                                                             \
  { GL2LDS(gB, &sB[bi][t8]); GL2LDS(gB + 65536, &sB[bi][t8 + 4096]); }
#define HALF2(p, kh)                                                          \
  {                                                                           \
    int co_ = ((kh)*32 + lq * 8) ^ csw;                                       \
    short8 a0_ = *(const short8*)&sA[p][ar + co_];                            \
    short8 a1_ = *(const short8*)&sA[p][ar + 1024 + co_];                     \
    short8 b0_ = *(const short8*)&sB[p][br + 0 + co_];                        \
    short8 b1_ = *(const short8*)&sB[p][br + 1024 + co_];                     \
    short8 b2_ = *(const short8*)&sB[p][br + 2048 + co_];                     \
    short8 b3_ = *(const short8*)&sB[p][br + 3072 + co_];                     \
    acc[0][0] = __builtin_amdgcn_mfma_f32_16x16x32_bf16(a0_, b0_, acc[0][0], 0, 0, 0); \
    acc[1][0] = __builtin_amdgcn_mfma_f32_16x16x32_bf16(a1_, b0_, acc[1][0], 0, 0, 0); \
    acc[0][1] = __builtin_amdgcn_mfma_f32_16x16x32_bf16(a0_, b1_, acc[0][1], 0, 0, 0); \
    acc[1][1] = __builtin_amdgcn_mfma_f32_16x16x32_bf16(a1_, b1_, acc[1][1], 0, 0, 0); \
    acc[0][2] = __builtin_amdgcn_mfma_f32_16x16x32_bf16(a0_, b2_, acc[0][2], 0, 0, 0); \
    acc[1][2] = __builtin_amdgcn_mfma_f32_16x16x32_bf16(a1_, b2_, acc[1][2], 0, 0, 0); \
    acc[0][3] = __builtin_amdgcn_mfma_f32_16x16x32_bf16(a0_, b3_, acc[0][3], 0, 0, 0); \
    acc[1][3] = __builtin_amdgcn_mfma_f32_16x16x32_bf16(a1_, b3_, acc[1][3], 0, 0, 0); \
  }
#define KT2(p, q, DOST)                                                       \
  {                                                                           \
    if (DOST) { ST_A2(q); ST_B2(q); gA += 64; gB += 64; }                     \
    BARX; __builtin_amdgcn_s_setprio(1);                                      \
    HALF2(p, 0);                                                              \
    __builtin_amdgcn_s_setprio(0); BARX;                                      \
    __builtin_amdgcn_s_setprio(1);                                            \
    HALF2(p, 1);                                                              \
    __builtin_amdgcn_s_setprio(0); VM0BARX;                                   \
  }

  ST_A2(0); ST_B2(0); gA += 64; gB += 64;  // K-tile 0
  VM0BARX;
#pragma unroll 1
  for (int t = 0; t < 7; ++t) {  // K-tiles 0..13
    KT2(0, 1, 1);
    KT2(1, 0, 1);
  }
  KT2(0, 1, 1);  // tile 14, stages 15
  KT2(1, 0, 0);  // tile 15

#pragma unroll
  for (int mi = 0; mi < 2; mi++)
#pragma unroll
    for (int ni = 0; ni < 4; ni++) {
      int row = bm + wm * 32 + mi * 16 + lq * 4;
      int col = bn + wn * 64 + ni * 16 + lr;
#pragma unroll
      for (int r = 0; r < 4; r++)
        C[(size_t)(row + r) * 1024 + col] = acc[mi][ni][r];
    }
}

// ------- flash attention (causal), linear softmax, exp2 domain -----------------
// r11 structure; change: the 2 row-sum MFMAs (mfma(ones,pb)) are replaced by
// VALU accumulation during the exp/pack loop (off the P-LDS dependency chain),
// with a single cross-lane shfl_xor(16)+shfl_xor(32) reduce AFTER the kt loop.
// 18 -> 16 MFMA/step; same sums, different order (within absmax tolerance).
#define LPT 64
__device__ __forceinline__ void attn_tile2(const u16* lK, const u16* lV, u16* lp,
                                           const short8* aq, floatx4* o,
                                           float& l_i, int lr, int lq,
                                           bool diag, int q0, int k0g) {
  floatx4 s[4];
#pragma unroll
  for (int ni = 0; ni < 4; ni++) {
    floatx4 a = {};
#pragma unroll
    for (int kc = 0; kc < 2; kc++) {
      int R = ni * 16 + lr;
      int c8 = (kc * 4 + lq) ^ (R & 7);
      short8 kf = *(const short8*)&lK[R * 64 + c8 * 8];
      a = __builtin_amdgcn_mfma_f32_16x16x32_bf16(kf, aq[kc], a, 0, 0, 0);
    }
    s[ni] = a;
  }
  if (diag) {
    int qg = q0 + lr;
#pragma unroll
    for (int ni = 0; ni < 4; ni++)
#pragma unroll
      for (int r = 0; r < 4; r++) {
        int kg = k0g + ni * 16 + lq * 4 + r;
        if (kg > qg) s[ni][r] = -1e30f;
      }
  }
  int swz = (lr & 7) << 3;
#pragma unroll
  for (int ni = 0; ni < 4; ni++) {
    float p0 = exp2f(s[ni][0]), p1 = exp2f(s[ni][1]);
    float p2 = exp2f(s[ni][2]), p3 = exp2f(s[ni][3]);
    l_i += (p0 + p1) + (p2 + p3);
    uint2v dw;
    dw.x = __builtin_amdgcn_perm(fu(p1), fu(p0), 0x07060302u);
    dw.y = __builtin_amdgcn_perm(fu(p3), fu(p2), 0x07060302u);
    *(uint2v*)&lp[lr * LPT + ((ni * 16 + lq * 4) ^ swz)] = dw;
  }
  short8 pb0 = *(const short8*)&lp[lr * LPT + ((lq * 8) ^ swz)];
  short8 pb1 = *(const short8*)&lp[lr * LPT + ((32 + lq * 8) ^ swz)];
#pragma unroll
  for (int di = 0; di < 4; di++) {
    int R = di * 16 + lr;
    int c80 = lq ^ (R & 7);
    int c81 = (4 + lq) ^ (R & 7);
    short8 v0 = *(const short8*)&lV[R * 64 + c80 * 8];
    o[di] = __builtin_amdgcn_mfma_f32_16x16x32_bf16(v0, pb0, o[di], 0, 0, 0);
    short8 v1 = *(const short8*)&lV[R * 64 + c81 * 8];
    o[di] = __builtin_amdgcn_mfma_f32_16x16x32_bf16(v1, pb1, o[di], 0, 0, 0);
  }
}

__global__ __launch_bounds__(256) void attn_k(const u16* __restrict__ qkv,
                                              u16* __restrict__ out) {
  __shared__ __align__(16) u16 lK[2][64 * 64];
  __shared__ __align__(16) u16 lV[2][64 * 64];
  __shared__ __align__(16) u16 lP[4][16 * LPT];
  int bh = blockIdx.x;
  int b = bh >> 4, h = bh & 15;
  int y = blockIdx.y;
  int g = y >> 3, o_ = y & 7;
  int j = (g & 1) ? ((g << 3) + 7 - o_) : y;  // balanced causal remap
  int tid = threadIdx.x;
  int w = tid >> 6, l = tid & 63;
  int lr = l & 15, lq = l >> 4;
  int q0 = j * 64 + w * 16;
  const u16* qb = qkv + (size_t)b * 2048 * 3072 + h * 64;
  const u16* kb = qkv + (size_t)b * 2048 * 3072 + 1024 + h * 64;
  int bh64 = bh * 64;
  short8 aq[2];
  aq[0] = *(const short8*)(qb + (size_t)(q0 + lr) * 3072 + lq * 8);
  aq[1] = *(const short8*)(qb + (size_t)(q0 + lr) * 3072 + 32 + lq * 8);
  floatx4 o[4] = {};
  float l_ = 0.0f;
  int srow8 = l >> 3;
  int sc8 = (l & 7) ^ srow8;
  u16* lp = &lP[w][0];
  // running staging pointers (tile to stage next)
  int row0 = w * 8 + srow8;        // m = w
  int row1 = (w + 4) * 8 + srow8;  // m = w+4
  const u16* kp0 = kb + (size_t)row0 * 3072 + sc8 * 8;
  const u16* kp1 = kb + (size_t)row1 * 3072 + sc8 * 8;
  const u16* vp0 = qkv + (size_t)((bh64 + row0) * 2) * 3072 + 2048 + sc8 * 8;
  const u16* vp1 = qkv + (size_t)((bh64 + row1) * 2) * 3072 + 2048 + sc8 * 8;
  auto stage = [&](int bufi) {
    GL2LDS(kp0, &lK[bufi][w * 512]);
    GL2LDS(vp0, &lV[bufi][w * 512]);
    GL2LDS(kp1, &lK[bufi][(w + 4) * 512]);
    GL2LDS(vp1, &lV[bufi][(w + 4) * 512]);
  };
  auto advance = [&](int ktStaged) {
    kp0 += 196608; kp1 += 196608;
    int dv = (((ktStaged + 1) & 15) == 0) ? 2112 : 64;
    vp0 += dv; vp1 += dv;
  };
  stage(0);
  advance(0);
  for (int kt = 0; kt <= j; ++kt) {
    int cur = kt & 1;
    __syncthreads();  // publishes buf[cur], guards reuse of buf[cur^1]
    if (kt < j) { stage(cur ^ 1); advance(kt + 1); }
    attn_tile2(lK[cur], lV[cur], lp, aq, o, l_, lr, lq, kt == j, q0, kt * 64);
  }
  // cross-lane row-sum: lanes sharing lr (4 lq groups) hold partial sums
  l_ += __shfl_xor(l_, 16, 64);
  l_ += __shfl_xor(l_, 32, 64);
  float rl = 1.0f / l_;
#pragma unroll
  for (int di = 0; di < 4; di++) {
    uint2v dw;
    u16 a0 = f2bf(o[di][0] * rl), a1 = f2bf(o[di][1] * rl);
    u16 a2 = f2bf(o[di][2] * rl), a3 = f2bf(o[di][3] * rl);
    dw.x = (uint32_t)a0 | ((uint32_t)a1 << 16);
    dw.y = (uint32_t)a2 | ((uint32_t)a3 << 16);
    int dcol = h * 64 + di * 16 + lq * 4;
    *(uint2v*)(out + ((size_t)(b * 2048 + q0 + lr)) * 1024 + dcol) = dw;
  }
}

// ------- launch ---------------------------------------------------------------
extern "C" void kernel_launch(void* const* d_in, const int* in_sizes, int n_in,
                              void* d_out, int out_size, void* d_ws, size_t ws_size,
                              hipStream_t stream) {
  const float* x = (const float*)d_in[0];
  const float* gamma = (const float*)d_in[1];
  const float* beta = (const float*)d_in[2];
  const float* Wq = (const float*)d_in[3];
  const float* Wkv = (const float*)d_in[4];
  const float* Wo = (const float*)d_in[5];
  float* out = (float*)d_out;
  char* ws = (char*)d_ws;

  u16* qkv = (u16*)(ws);               // 4096x3072 bf16 = 24 MiB (v-slice holds packed vT)
  u16* wqkvT = (u16*)(ws + 25165824);  // 3072x1024 = 6 MiB
  u16* woT = (u16*)(ws + 31457280);    // 1024x1024 = 2 MiB
  u16* xn = (u16*)(ws + 33554432);     // 4096x1024 = 8 MiB
  u16* attn_out = xn;                  // alias: xn dead after gemm_qkv (4096x1024 bf16)

  prep_k<<<5120, 256, 0, stream>>>(x, gamma, beta, Wq, Wkv, Wo, xn, wqkvT, woT);
  gemm_qkv_k<<<256, 512, 0, stream>>>(xn, wqkvT, qkv);
  attn_k<<<dim3(32, 32), 256, 0, stream>>>(qkv, attn_out);
  gemm64_bf16_k<<<256, 512, 0, stream>>>(attn_out, woT, out);
}